// Round 13
// baseline (122.170 us; speedup 1.0000x reference)
//
#include <hip/hip_runtime.h>
#include <math.h>

#define CEXP 2.8853900817779268f  // 2*log2(e): tanh(z) = 1 - 2/(2^(c*z)+1)
#define TABN 2048   // s(theta) table cells
#define NC   255    // w(x) grid cells per axis: NN=256 -> NNODES=65536 = 256
                    // blocks of 256 w-threads EXACTLY (1 block/CU, no tail).
#define NN   256    // w(x) grid nodes per axis
#define NNODES (NN * NN)                 // 65536
#define NCELLS (NC * NC)                 // 65025
#define WBLK (NNODES / 256)              // 256 blocks total -- grid == CU count

// Tables (rewritten every launch; kernel boundaries make them visible across
// XCDs). g_ctab[node] = {w0+y*w4, .., w3+y*w7} (yita folded, 16 B/node).
// g_qtab[cell] = 32 B quad record {c00: 4xf32 | d10: 4xbf16 | d01: 4xbf16}
// so interior reads ONE aligned 32 B line per point.
__device__ float4 g_ctab[NNODES];
__device__ float4 g_qtab[NCELLS * 2];   // 2.1 MB, L2-resident per XCD
__device__ float2 g_stab2[TABN];        // cell i: {s(p_i), s(p_{i+1}) - s(p_i)}

// tanh with the 2*log2(e) factor pre-folded into the incoming accumulator.
static __device__ __forceinline__ float tanh_pre(float z) {
    float e = __builtin_amdgcn_exp2f(z);
    float r = __builtin_amdgcn_rcpf(e + 1.0f);
    return fmaf(-2.0f, r, 1.0f);
}

// pack two floats to bf16 (round-to-nearest-even) in one uint {lo=a, hi=b}
static __device__ __forceinline__ unsigned bf16x2(float a, float b) {
    unsigned ua = __float_as_uint(a);
    ua = (ua + 0x7FFFu + ((ua >> 16) & 1u)) >> 16;
    unsigned ub = __float_as_uint(b);
    ub = (ub + 0x7FFFu + ((ub >> 16) & 1u)) & 0xFFFF0000u;
    return ua | ub;
}

// Full phi-branch value s(theta(p)) at diamond-angle parameter p in [-2,2].
// ROUND-2 LESSON: keep this UN-unrolled with libm tanhf (the unrolled
// tanh_pre version spilled to scratch). Callers pass LDS-staged weight
// pointers (round-11 win).
static __device__ float s_of_p(float pth,
    const float* __restrict__ Wp1, const float* __restrict__ bp1,
    const float* __restrict__ Wp2, const float* __restrict__ bp2,
    const float* __restrict__ Wp3, const float* __restrict__ bp3,
    const float* __restrict__ Wp4, const float* __restrict__ bp4)
{
    float th;
    if (pth >= -1.0f && pth <= 1.0f) {
        th = atanf(pth / (1.0f - fabsf(pth)));      // /0 -> inf -> atan=pi/2 ok
    } else if (pth > 1.0f) {
        const float uu = 2.0f - pth;                // [0,1)
        th = (float)M_PI - atanf(uu / (1.0f - uu));
    } else {
        const float uu = -2.0f - pth;               // (-1,0]
        th = -(float)M_PI + atanf(-uu / (1.0f + uu));
    }
    const float cth = cosf(th), sth = sinf(th);

    // phi-MLP in f32 with exact tanh: 2 -> 15 -> 15 -> 15 -> 4
    float h[15], h2[15];
    for (int j = 0; j < 15; ++j)
        h[j] = tanhf(cth * Wp1[j] + sth * Wp1[15 + j] + bp1[j]);
    for (int j = 0; j < 15; ++j) {
        float a = bp2[j];
        for (int k = 0; k < 15; ++k) a += h[k] * Wp2[k * 15 + j];
        h2[j] = tanhf(a);
    }
    for (int j = 0; j < 15; ++j) {
        float a = bp3[j];
        for (int k = 0; k < 15; ++k) a += h2[k] * Wp3[k * 15 + j];
        h[j] = tanhf(a);
    }
    float ph[4];
    for (int j = 0; j < 4; ++j) {
        float a = bp4[j];
        for (int k = 0; k < 15; ++k) a += h[k] * Wp4[k * 4 + j];
        ph[j] = a;
    }
    return ph[0] + ph[1] * sinf(0.5f * th) + ph[2] * sth + ph[3] * sinf(1.5f * th);
}

// ROUND-13 STRUCTURE: grid == 256 blocks EXACTLY, 320 threads (5 waves).
// Round-12's ledger showed prep ~27us = w-chain(15) + s-chain(12) STACKED:
// the 9 extra s-table blocks (grid 265 > 256 CUs) ran serially after a full
// w-block on 9 CUs. Fix: fold the s-table into a 5th wave of each block --
// 8 cells/block x 256 blocks = 2048; lanes 0-8 of the 5th wave each run one
// s_of_p eval (lanes 9-63 redundantly compute the clamped boundary eval;
// uniform control flow), __shfl_down provides the neighbor, lanes 0-7 store.
// s-chain now runs CONCURRENT with the w-chains -> makespan = max, not sum.
// w-branch (threads 0-255): byte-identical to round-12 (b128 reads, 1
// node/thread). Table values bit-identical (same s_of_p, same inputs).
__global__ __launch_bounds__(320) void prep_kernel(
    const float* __restrict__ imv,
    const float* __restrict__ Ww1, const float* __restrict__ bw1,
    const float* __restrict__ Ww2, const float* __restrict__ bw2,
    const float* __restrict__ Ww3, const float* __restrict__ bw3,
    const float* __restrict__ Ww4, const float* __restrict__ bw4,
    const float* __restrict__ Wp1, const float* __restrict__ bp1,
    const float* __restrict__ Wp2, const float* __restrict__ bp2,
    const float* __restrict__ Wp3, const float* __restrict__ bp3,
    const float* __restrict__ Wp4, const float* __restrict__ bp4)
{
    const int t = threadIdx.x;

    // ---- LDS: w-MLP weights ([k][32] padded) + phi-MLP weights ----
    __shared__ __align__(16) float sW1[60], sb1[30];
    __shared__ __align__(16) float sW2[30 * 32], sb2[30];
    __shared__ __align__(16) float sW3[30 * 32], sb3[30];
    __shared__ __align__(16) float sW4[240], sb4[8];
    __shared__ float pW1[30], pb1[15], pW2[225], pb2[15],
                     pW3[225], pb3[15], pW4[60], pb4[4];

    if (t < 256) {
        // w-weight staging (threads 0-255, as in round 12)
        for (int i = t; i < 960; i += 256) {
            const int k = i >> 5, c = i & 31;
            const bool pad = (c >= 30);
            sW2[i] = pad ? 0.0f : CEXP * Ww2[k * 30 + c];
            sW3[i] = pad ? 0.0f : CEXP * Ww3[k * 30 + c];
        }
        if (t < 240) sW4[t] = Ww4[t];
        if (t < 60) sW1[t] = CEXP * Ww1[t];
        if (t < 30) {
            sb1[t] = CEXP * bw1[t];
            sb2[t] = CEXP * bw2[t];
            sb3[t] = CEXP * bw3[t];
        }
        if (t < 8) sb4[t] = bw4[t];
    } else {
        // phi-weight staging (5th wave, 64 lanes)
        const int u = t - 256;
        for (int i = u; i < 225; i += 64) { pW2[i] = Wp2[i]; pW3[i] = Wp3[i]; }
        if (u < 60) pW4[u] = Wp4[u];
        if (u < 30) pW1[u] = Wp1[u];
        if (u < 15) { pb1[u] = bp1[u]; pb2[u] = bp2[u]; pb3[u] = bp3[u]; }
        if (u < 4)  pb4[u] = bp4[u];
    }
    __syncthreads();

    if (t < 256) {
        const int gid = blockIdx.x * 256 + t;      // always < NNODES (exact fit)
        const int ix = gid & 255, iy = gid >> 8;   // NN = 256: free indexing
        const float x0 = (float)ix * (1.0f / (float)NC);
        const float x1 = (float)iy * (1.0f / (float)NC);

        float h[30], a[30];
        #pragma unroll
        for (int j = 0; j < 30; ++j)
            h[j] = tanh_pre(fmaf(x1, sW1[30 + j], fmaf(x0, sW1[j], sb1[j])));

        // layer 2: 30 -> 30, 8x ds_read_b128 per k
        #pragma unroll
        for (int j = 0; j < 30; ++j) a[j] = sb2[j];
        #pragma unroll
        for (int k = 0; k < 30; ++k) {
            const float hk = h[k];
            const float* Wr = &sW2[k * 32];
            #pragma unroll
            for (int q = 0; q < 7; ++q) {
                const float4 w = *(const float4*)&Wr[4 * q];
                a[4 * q]     = fmaf(hk, w.x, a[4 * q]);
                a[4 * q + 1] = fmaf(hk, w.y, a[4 * q + 1]);
                a[4 * q + 2] = fmaf(hk, w.z, a[4 * q + 2]);
                a[4 * q + 3] = fmaf(hk, w.w, a[4 * q + 3]);
            }
            const float4 w7 = *(const float4*)&Wr[28];
            a[28] = fmaf(hk, w7.x, a[28]);
            a[29] = fmaf(hk, w7.y, a[29]);
        }
        #pragma unroll
        for (int j = 0; j < 30; ++j) a[j] = tanh_pre(a[j]);

        // layer 3: 30 -> 30
        #pragma unroll
        for (int j = 0; j < 30; ++j) h[j] = sb3[j];
        #pragma unroll
        for (int k = 0; k < 30; ++k) {
            const float ak = a[k];
            const float* Wr = &sW3[k * 32];
            #pragma unroll
            for (int q = 0; q < 7; ++q) {
                const float4 w = *(const float4*)&Wr[4 * q];
                h[4 * q]     = fmaf(ak, w.x, h[4 * q]);
                h[4 * q + 1] = fmaf(ak, w.y, h[4 * q + 1]);
                h[4 * q + 2] = fmaf(ak, w.z, h[4 * q + 2]);
                h[4 * q + 3] = fmaf(ak, w.w, h[4 * q + 3]);
            }
            const float4 w7 = *(const float4*)&Wr[28];
            h[28] = fmaf(ak, w7.x, h[28]);
            h[29] = fmaf(ak, w7.y, h[29]);
        }
        #pragma unroll
        for (int j = 0; j < 30; ++j) h[j] = tanh_pre(h[j]);

        // layer 4: 30 -> 8, 2x ds_read_b128 per k
        float o[8];
        #pragma unroll
        for (int j = 0; j < 8; ++j) o[j] = sb4[j];
        #pragma unroll
        for (int k = 0; k < 30; ++k) {
            const float hk = h[k];
            const float4 wA = *(const float4*)&sW4[k * 8];
            const float4 wB = *(const float4*)&sW4[k * 8 + 4];
            o[0] = fmaf(hk, wA.x, o[0]); o[1] = fmaf(hk, wA.y, o[1]);
            o[2] = fmaf(hk, wA.z, o[2]); o[3] = fmaf(hk, wA.w, o[3]);
            o[4] = fmaf(hk, wB.x, o[4]); o[5] = fmaf(hk, wB.y, o[5]);
            o[6] = fmaf(hk, wB.z, o[6]); o[7] = fmaf(hk, wB.w, o[7]);
        }

        // ---- fold yita(node): c_j = w_j + y * w_{4+j}  (16 B/node) ----
        const float ddx = x0 - imv[0], ddy = x1 - imv[1];
        const float rr  = sqrtf(fmaf(ddx, ddx, ddy * ddy));
        const float tt  = fminf(fmaxf(fmaf(2.5f, rr, -1.25f), 0.0f), 1.0f);
        const float tt3 = tt * tt * tt;
        const float yv  = fmaf(fmaf(fmaf(-6.0f, tt, 15.0f), tt, -10.0f), tt3, 1.0f);

        float4 v;
        v.x = fmaf(yv, o[4], o[0]);
        v.y = fmaf(yv, o[5], o[1]);
        v.z = fmaf(yv, o[6], o[2]);
        v.w = fmaf(yv, o[7], o[3]);
        g_ctab[gid] = v;
        return;
    }

    // ---- 5th wave: 8 s(theta) cells for this block ----
    const int u = t - 256;                       // lane 0..63
    const int evl = u < 8 ? u : 8;               // lanes 8-63: boundary eval
    const int ev  = blockIdx.x * 8 + evl;        // 0..2048
    const float hh = 4.0f / (float)TABN;
    const float pe = -2.0f + hh * (float)ev;
    const float s  = s_of_p(pe, pW1, pb1, pW2, pb2, pW3, pb3, pW4, pb4);
    const float s1 = __shfl_down(s, 1);          // lane u reads lane u+1
    if (u < 8) {
        float2 e; e.x = s; e.y = s1 - s;
        g_stab2[blockIdx.x * 8 + u] = e;
    }
}

// Cell-quad packing: node table -> 32 B/cell {c00 f32x4, d10 bf16x4, d01
// bf16x4}. Coalesced reads/writes, ~1.5us. Separate launch = visibility of
// g_ctab across XCDs. NN=256: node index is shifts only.
__global__ __launch_bounds__(256) void pack_kernel() {
    const int c = blockIdx.x * 256 + threadIdx.x;
    if (c >= NCELLS) return;
    const int ix = c % NC, iy = c / NC;
    const int n = (iy << 8) + ix;
    const float4 c00 = g_ctab[n];
    const float4 c10 = g_ctab[n + 1];
    const float4 c01 = g_ctab[n + NN];
    float4 d;
    d.x = __uint_as_float(bf16x2(c10.x - c00.x, c10.y - c00.y));
    d.y = __uint_as_float(bf16x2(c10.z - c00.z, c10.w - c00.w));
    d.z = __uint_as_float(bf16x2(c01.x - c00.x, c01.y - c00.y));
    d.w = __uint_as_float(bf16x2(c01.z - c00.z, c01.w - c00.w));
    g_qtab[2 * c]     = c00;
    g_qtab[2 * c + 1] = d;
}

// 2 points per thread. Per point: ONE aligned 32 B quad load, one 8 B
// s(theta) gather (16 KB table, L1-resident), ~60 VALU.
__global__ __launch_bounds__(256) void interior_kernel(
    const float4* __restrict__ x,      // two points per float4
    const float*  __restrict__ imv,
    const float*  __restrict__ lmbd,
    float* __restrict__ out, int n2)   // n2 = n/2
{
    const int idx = blockIdx.x * blockDim.x + threadIdx.x;
    if (idx >= n2) return;

    const float4 xx = x[idx];
    const float X0[2] = {xx.x, xx.z};
    const float X1[2] = {xx.y, xx.w};
    const float im0 = imv[0], im1 = imv[1], lam = lmbd[0];

    const float4* __restrict__ Q = g_qtab;

    float res[2];
    #pragma unroll
    for (int p = 0; p < 2; ++p) {
        const float x0 = X0[p], x1 = X1[p];

        // ---- one-line gather of the folded cell quad ----
        const float fx = x0 * (float)NC;
        const float fy = x1 * (float)NC;
        int ix = (int)fx; ix = ix < 0 ? 0 : (ix > NC - 1 ? NC - 1 : ix);
        int iy = (int)fy; iy = iy < 0 ? 0 : (iy > NC - 1 ? NC - 1 : iy);
        const float frx = fx - (float)ix;
        const float fry = fy - (float)iy;

        const int cell = iy * NC + ix;
        const float4 c00 = Q[2 * cell];
        const float4 dd  = Q[2 * cell + 1];
        const unsigned ux = __float_as_uint(dd.x), uy = __float_as_uint(dd.y);
        const unsigned uz = __float_as_uint(dd.z), uw = __float_as_uint(dd.w);

        float cv[4];
        cv[0] = fmaf(frx, __uint_as_float(ux << 16),
                fmaf(fry, __uint_as_float(uz << 16),          c00.x));
        cv[1] = fmaf(frx, __uint_as_float(ux & 0xFFFF0000u),
                fmaf(fry, __uint_as_float(uz & 0xFFFF0000u),  c00.y));
        cv[2] = fmaf(frx, __uint_as_float(uy << 16),
                fmaf(fry, __uint_as_float(uw << 16),          c00.z));
        cv[3] = fmaf(frx, __uint_as_float(uy & 0xFFFF0000u),
                fmaf(fry, __uint_as_float(uw & 0xFFFF0000u),  c00.w));

        // ---- geometry about the interior vertex ----
        const float dx = x0 - im0, dy = x1 - im1;
        const float r  = sqrtf(fmaf(dx, dx, dy * dy));

        // yita(r) -- exact, still needed for the sp term
        const float t  = fminf(fmaxf(fmaf(2.5f, r, -1.25f), 0.0f), 1.0f);
        const float t3 = t * t * t;
        const float yv = fmaf(fmaf(fmaf(-6.0f, t, 15.0f), t, -10.0f), t3, 1.0f);

        // r^lambda (sqrt fast path for lambda == 0.5)
        float rl;
        if (lam == 0.5f) rl = sqrtf(r);
        else rl = __builtin_amdgcn_exp2f(lam * __builtin_amdgcn_logf(fmaxf(r, 1e-20f)));

        // diamond-angle parameter p(theta) in [-2,2], no trig
        const float l1n = fmaxf(fabsf(dx) + fabsf(dy), 1e-20f);
        const float u   = dy * __builtin_amdgcn_rcpf(l1n);
        const float pbk = (dy >= 0.0f) ? (2.0f - u) : (-2.0f - u);
        const float pth = (dx >= 0.0f) ? u : pbk;

        // s(theta) table gather: cell {s, ds}, one 8 B load
        const float fi = fminf(fmaxf(fmaf(pth, (float)(TABN / 4), (float)(TABN / 2)),
                                     0.0f), (float)TABN - 0.001f);
        const int   ii = (int)fi;
        const float fr = fi - (float)ii;
        const float2 sd = g_stab2[ii];
        const float sval = fmaf(fr, sd.y, sd.x);

        // singular functions at x (about origin), algebraically reduced:
        // vp0 = r0^0.5 sin(th/2) = copysign(sqrt((r0-x0)/2), x1)
        // vp1 = x1
        // vp2 = r0^1.5 sin(1.5 th) = x1*sqrt((r0+x0)/2) + x0*vp0
        const float r0 = sqrtf(fmaf(x0, x0, x1 * x1));
        const float Aq = sqrtf(fmaxf(0.0f, (r0 - x0) * 0.5f));
        const float Bq = sqrtf(fmaxf(0.0f, (r0 + x0) * 0.5f));
        const float vp0 = copysignf(Aq, x1);
        const float vp2 = fmaf(x1, Bq, x0 * vp0);

        // combine (yita already folded into cv[])
        float rp = cv[0];
        rp = fmaf(cv[1], vp0, rp);
        rp = fmaf(cv[2], x1, rp);
        rp = fmaf(cv[3], vp2, rp);
        res[p] = fmaf(sval * yv, rl, rp);
    }

    float2 o; o.x = res[0]; o.y = res[1];
    ((float2*)out)[idx] = o;
}

extern "C" void kernel_launch(void* const* d_in, const int* in_sizes, int n_in,
                              void* d_out, int out_size, void* d_ws, size_t ws_size,
                              hipStream_t stream) {
    const float4* x   = (const float4*)d_in[0];
    const float* imv  = (const float*)d_in[1];
    const float* lmbd = (const float*)d_in[2];
    const float* Ww1  = (const float*)d_in[3];
    const float* bw1  = (const float*)d_in[4];
    const float* Ww2  = (const float*)d_in[5];
    const float* bw2  = (const float*)d_in[6];
    const float* Ww3  = (const float*)d_in[7];
    const float* bw3  = (const float*)d_in[8];
    const float* Ww4  = (const float*)d_in[9];
    const float* bw4  = (const float*)d_in[10];
    const float* Wp1  = (const float*)d_in[11];
    const float* bp1  = (const float*)d_in[12];
    const float* Wp2  = (const float*)d_in[13];
    const float* bp2  = (const float*)d_in[14];
    const float* Wp3  = (const float*)d_in[15];
    const float* bp3  = (const float*)d_in[16];
    const float* Wp4  = (const float*)d_in[17];
    const float* bp4  = (const float*)d_in[18];
    float* out = (float*)d_out;

    const int n  = in_sizes[0] / 2;
    const int n2 = n / 2;

    // prep (256 blocks x 320 threads: 4 w-waves + 1 s-wave) -> pack -> interior.
    prep_kernel<<<WBLK, 320, 0, stream>>>(
        imv,
        Ww1, bw1, Ww2, bw2, Ww3, bw3, Ww4, bw4,
        Wp1, bp1, Wp2, bp2, Wp3, bp3, Wp4, bp4);

    pack_kernel<<<(NCELLS + 255) / 256, 256, 0, stream>>>();

    const int block = 256;
    const int grid = (n2 + block - 1) / block;
    interior_kernel<<<grid, block, 0, stream>>>(x, imv, lmbd, out, n2);
}

// Round 14
// 119.832 us; speedup vs baseline: 1.0195x; 1.0195x over previous
//
#include <hip/hip_runtime.h>
#include <hip/hip_fp16.h>
#include <math.h>

#define CEXP 2.8853900817779268f  // 2*log2(e): tanh(z) = 1 - 2/(2^(c*z)+1)
#define TABN 2048   // s(theta) table cells
#define NC   255    // w(x) grid cells per axis: NN=256 -> NNODES=65536 = 256
                    // blocks of 256 threads EXACTLY (1 block/CU, no tail).
#define NN   256    // w(x) grid nodes per axis
#define NNODES (NN * NN)                 // 65536
#define NCELLS (NC * NC)                 // 65025
#define WBLK (NNODES / 256)              // 256 fat blocks for the w-grid
#define SBLK ((TABN + 254) / 255)        // 9 s-table blocks (255 cells each)

// Tables (rewritten every launch; kernel boundaries make them visible across
// XCDs). g_ctab[node] = {w0+y*w4, .., w3+y*w7} (yita folded, 16 B/node).
// g_qtab[cell] = 32 B quad record {c00: 4xf32 | d10: 4xbf16 | d01: 4xbf16}
// so interior reads ONE aligned 32 B line per point.
__device__ float4 g_ctab[NNODES];
__device__ float4 g_qtab[NCELLS * 2];   // 2.1 MB, L2-resident per XCD
__device__ float2 g_stab2[TABN];        // cell i: {s(p_i), s(p_{i+1}) - s(p_i)}

// tanh with the 2*log2(e) factor pre-folded into the incoming accumulator.
static __device__ __forceinline__ float tanh_pre(float z) {
    float e = __builtin_amdgcn_exp2f(z);
    float r = __builtin_amdgcn_rcpf(e + 1.0f);
    return fmaf(-2.0f, r, 1.0f);
}

// pack two floats to bf16 (round-to-nearest-even) in one uint {lo=a, hi=b}
static __device__ __forceinline__ unsigned bf16x2(float a, float b) {
    unsigned ua = __float_as_uint(a);
    ua = (ua + 0x7FFFu + ((ua >> 16) & 1u)) >> 16;
    unsigned ub = __float_as_uint(b);
    ub = (ub + 0x7FFFu + ((ub >> 16) & 1u)) & 0xFFFF0000u;
    return ua | ub;
}

// unpack 2 f16 (packed in one uint) to 2 f32
static __device__ __forceinline__ float2 h2f2(unsigned u) {
    const __half2 hh = *reinterpret_cast<const __half2*>(&u);
    return __half22float2(hh);
}

// Full phi-branch value s(theta(p)) at diamond-angle parameter p in [-2,2].
// ROUND-2 LESSON: keep this UN-unrolled with libm tanhf (the unrolled
// tanh_pre version spilled to scratch). Callers pass LDS-staged weight
// pointers (round-11 win, -8us).
static __device__ float s_of_p(float pth,
    const float* __restrict__ Wp1, const float* __restrict__ bp1,
    const float* __restrict__ Wp2, const float* __restrict__ bp2,
    const float* __restrict__ Wp3, const float* __restrict__ bp3,
    const float* __restrict__ Wp4, const float* __restrict__ bp4)
{
    float th;
    if (pth >= -1.0f && pth <= 1.0f) {
        th = atanf(pth / (1.0f - fabsf(pth)));      // /0 -> inf -> atan=pi/2 ok
    } else if (pth > 1.0f) {
        const float uu = 2.0f - pth;                // [0,1)
        th = (float)M_PI - atanf(uu / (1.0f - uu));
    } else {
        const float uu = -2.0f - pth;               // (-1,0]
        th = -(float)M_PI + atanf(-uu / (1.0f + uu));
    }
    const float cth = cosf(th), sth = sinf(th);

    // phi-MLP in f32 with exact tanh: 2 -> 15 -> 15 -> 15 -> 4
    float h[15], h2[15];
    for (int j = 0; j < 15; ++j)
        h[j] = tanhf(cth * Wp1[j] + sth * Wp1[15 + j] + bp1[j]);
    for (int j = 0; j < 15; ++j) {
        float a = bp2[j];
        for (int k = 0; k < 15; ++k) a += h[k] * Wp2[k * 15 + j];
        h2[j] = tanhf(a);
    }
    for (int j = 0; j < 15; ++j) {
        float a = bp3[j];
        for (int k = 0; k < 15; ++k) a += h2[k] * Wp3[k * 15 + j];
        h[j] = tanhf(a);
    }
    float ph[4];
    for (int j = 0; j < 4; ++j) {
        float a = bp4[j];
        for (int k = 0; k < 15; ++k) a += h[k] * Wp4[k * 4 + j];
        ph[j] = a;
    }
    return ph[0] + ph[1] * sinf(0.5f * th) + ph[2] * sth + ph[3] * sinf(1.5f * th);
}

// w-grid prep: ROUND-12 base (best, 121.05us) with the LDS read-EVENT count
// halved again: R12's per-thread chain had ~630 latency-serialized reads
// (layer1: 90 scalar b32!; layers 2/3: 8x b128/k; layer4: 2x b128/k).
// Round 14: (a) layer-1 weights interleaved {wa,wb,b,0} -> 30 b128 reads;
// (b) layers 2/3 stored as f16 [30][32] halves (64 B/row) -> 4x b128/k,
// unpacked via __half22float2 before the SAME-order FMAs. ~320 events total.
// f16 weight rel-err 4.9e-4, RMS-propagated through the contractive tanh
// stack ~1-3e-4 on outputs -- well under the 6.13e-3 threshold (current
// absmax sits at the 1.95e-3 bf16 floor with 3.1x margin). Biases and
// layers 1/4 stay f32. s-branch: round-11/12 winner, untouched.
__global__ __launch_bounds__(256) void prep_kernel(
    const float* __restrict__ imv,
    const float* __restrict__ Ww1, const float* __restrict__ bw1,
    const float* __restrict__ Ww2, const float* __restrict__ bw2,
    const float* __restrict__ Ww3, const float* __restrict__ bw3,
    const float* __restrict__ Ww4, const float* __restrict__ bw4,
    const float* __restrict__ Wp1, const float* __restrict__ bp1,
    const float* __restrict__ Wp2, const float* __restrict__ bp2,
    const float* __restrict__ Wp3, const float* __restrict__ bp3,
    const float* __restrict__ Wp4, const float* __restrict__ bp4)
{
    const int t = threadIdx.x;

    if (blockIdx.x < WBLK) {
        // ---- stage weights into LDS ----
        // sL1[j] = {CEXP*wa_j, CEXP*wb_j, CEXP*b_j, 0}: one b128 per j.
        // sW2h/sW3h: f16, [k][32] padded (cols 30,31 = 0): 4 b128 per k.
        __shared__ __align__(16) float4 sL1[30];
        __shared__ __align__(16) __half sW2h[30 * 32];
        __shared__ __align__(16) __half sW3h[30 * 32];
        __shared__ __align__(16) float sb2[30], sb3[30], sW4[240], sb4[8];
        for (int i = t; i < 960; i += 256) {
            const int k = i >> 5, c = i & 31;
            const bool pad = (c >= 30);
            sW2h[i] = __float2half(pad ? 0.0f : CEXP * Ww2[k * 30 + c]);
            sW3h[i] = __float2half(pad ? 0.0f : CEXP * Ww3[k * 30 + c]);
        }
        if (t < 240) sW4[t] = Ww4[t];
        if (t < 30) {
            float4 L; L.x = CEXP * Ww1[t]; L.y = CEXP * Ww1[30 + t];
            L.z = CEXP * bw1[t]; L.w = 0.0f;
            sL1[t] = L;
            sb2[t] = CEXP * bw2[t];
            sb3[t] = CEXP * bw3[t];
        }
        if (t < 8) sb4[t] = bw4[t];
        __syncthreads();

        const int gid = blockIdx.x * 256 + t;      // always < NNODES (exact fit)
        const int ix = gid & 255, iy = gid >> 8;   // NN = 256: free indexing
        const float x0 = (float)ix * (1.0f / (float)NC);
        const float x1 = (float)iy * (1.0f / (float)NC);

        float h[30], a[30];
        #pragma unroll
        for (int j = 0; j < 30; ++j) {
            const float4 w = sL1[j];
            h[j] = tanh_pre(fmaf(x1, w.y, fmaf(x0, w.x, w.z)));
        }

        // layer 2: 30 -> 30, 4x ds_read_b128 per k (f16 weights)
        #pragma unroll
        for (int j = 0; j < 30; ++j) a[j] = sb2[j];
        #pragma unroll
        for (int k = 0; k < 30; ++k) {
            const float hk = h[k];
            const __half* Wr = &sW2h[k * 32];
            const uint4 q0 = *(const uint4*)&Wr[0];
            const uint4 q1 = *(const uint4*)&Wr[8];
            const uint4 q2 = *(const uint4*)&Wr[16];
            const uint4 q3 = *(const uint4*)&Wr[24];
            float2 f;
            f = h2f2(q0.x); a[0]  = fmaf(hk, f.x, a[0]);  a[1]  = fmaf(hk, f.y, a[1]);
            f = h2f2(q0.y); a[2]  = fmaf(hk, f.x, a[2]);  a[3]  = fmaf(hk, f.y, a[3]);
            f = h2f2(q0.z); a[4]  = fmaf(hk, f.x, a[4]);  a[5]  = fmaf(hk, f.y, a[5]);
            f = h2f2(q0.w); a[6]  = fmaf(hk, f.x, a[6]);  a[7]  = fmaf(hk, f.y, a[7]);
            f = h2f2(q1.x); a[8]  = fmaf(hk, f.x, a[8]);  a[9]  = fmaf(hk, f.y, a[9]);
            f = h2f2(q1.y); a[10] = fmaf(hk, f.x, a[10]); a[11] = fmaf(hk, f.y, a[11]);
            f = h2f2(q1.z); a[12] = fmaf(hk, f.x, a[12]); a[13] = fmaf(hk, f.y, a[13]);
            f = h2f2(q1.w); a[14] = fmaf(hk, f.x, a[14]); a[15] = fmaf(hk, f.y, a[15]);
            f = h2f2(q2.x); a[16] = fmaf(hk, f.x, a[16]); a[17] = fmaf(hk, f.y, a[17]);
            f = h2f2(q2.y); a[18] = fmaf(hk, f.x, a[18]); a[19] = fmaf(hk, f.y, a[19]);
            f = h2f2(q2.z); a[20] = fmaf(hk, f.x, a[20]); a[21] = fmaf(hk, f.y, a[21]);
            f = h2f2(q2.w); a[22] = fmaf(hk, f.x, a[22]); a[23] = fmaf(hk, f.y, a[23]);
            f = h2f2(q3.x); a[24] = fmaf(hk, f.x, a[24]); a[25] = fmaf(hk, f.y, a[25]);
            f = h2f2(q3.y); a[26] = fmaf(hk, f.x, a[26]); a[27] = fmaf(hk, f.y, a[27]);
            f = h2f2(q3.z); a[28] = fmaf(hk, f.x, a[28]); a[29] = fmaf(hk, f.y, a[29]);
        }
        #pragma unroll
        for (int j = 0; j < 30; ++j) a[j] = tanh_pre(a[j]);

        // layer 3: 30 -> 30
        #pragma unroll
        for (int j = 0; j < 30; ++j) h[j] = sb3[j];
        #pragma unroll
        for (int k = 0; k < 30; ++k) {
            const float ak = a[k];
            const __half* Wr = &sW3h[k * 32];
            const uint4 q0 = *(const uint4*)&Wr[0];
            const uint4 q1 = *(const uint4*)&Wr[8];
            const uint4 q2 = *(const uint4*)&Wr[16];
            const uint4 q3 = *(const uint4*)&Wr[24];
            float2 f;
            f = h2f2(q0.x); h[0]  = fmaf(ak, f.x, h[0]);  h[1]  = fmaf(ak, f.y, h[1]);
            f = h2f2(q0.y); h[2]  = fmaf(ak, f.x, h[2]);  h[3]  = fmaf(ak, f.y, h[3]);
            f = h2f2(q0.z); h[4]  = fmaf(ak, f.x, h[4]);  h[5]  = fmaf(ak, f.y, h[5]);
            f = h2f2(q0.w); h[6]  = fmaf(ak, f.x, h[6]);  h[7]  = fmaf(ak, f.y, h[7]);
            f = h2f2(q1.x); h[8]  = fmaf(ak, f.x, h[8]);  h[9]  = fmaf(ak, f.y, h[9]);
            f = h2f2(q1.y); h[10] = fmaf(ak, f.x, h[10]); h[11] = fmaf(ak, f.y, h[11]);
            f = h2f2(q1.z); h[12] = fmaf(ak, f.x, h[12]); h[13] = fmaf(ak, f.y, h[13]);
            f = h2f2(q1.w); h[14] = fmaf(ak, f.x, h[14]); h[15] = fmaf(ak, f.y, h[15]);
            f = h2f2(q2.x); h[16] = fmaf(ak, f.x, h[16]); h[17] = fmaf(ak, f.y, h[17]);
            f = h2f2(q2.y); h[18] = fmaf(ak, f.x, h[18]); h[19] = fmaf(ak, f.y, h[19]);
            f = h2f2(q2.z); h[20] = fmaf(ak, f.x, h[20]); h[21] = fmaf(ak, f.y, h[21]);
            f = h2f2(q2.w); h[22] = fmaf(ak, f.x, h[22]); h[23] = fmaf(ak, f.y, h[23]);
            f = h2f2(q3.x); h[24] = fmaf(ak, f.x, h[24]); h[25] = fmaf(ak, f.y, h[25]);
            f = h2f2(q3.y); h[26] = fmaf(ak, f.x, h[26]); h[27] = fmaf(ak, f.y, h[27]);
            f = h2f2(q3.z); h[28] = fmaf(ak, f.x, h[28]); h[29] = fmaf(ak, f.y, h[29]);
        }
        #pragma unroll
        for (int j = 0; j < 30; ++j) h[j] = tanh_pre(h[j]);

        // layer 4: 30 -> 8, 2x ds_read_b128 per k (f32, unchanged)
        float o[8];
        #pragma unroll
        for (int j = 0; j < 8; ++j) o[j] = sb4[j];
        #pragma unroll
        for (int k = 0; k < 30; ++k) {
            const float hk = h[k];
            const float4 wA = *(const float4*)&sW4[k * 8];
            const float4 wB = *(const float4*)&sW4[k * 8 + 4];
            o[0] = fmaf(hk, wA.x, o[0]); o[1] = fmaf(hk, wA.y, o[1]);
            o[2] = fmaf(hk, wA.z, o[2]); o[3] = fmaf(hk, wA.w, o[3]);
            o[4] = fmaf(hk, wB.x, o[4]); o[5] = fmaf(hk, wB.y, o[5]);
            o[6] = fmaf(hk, wB.z, o[6]); o[7] = fmaf(hk, wB.w, o[7]);
        }

        // ---- fold yita(node): c_j = w_j + y * w_{4+j}  (16 B/node) ----
        const float ddx = x0 - imv[0], ddy = x1 - imv[1];
        const float rr  = sqrtf(fmaf(ddx, ddx, ddy * ddy));
        const float tt  = fminf(fmaxf(fmaf(2.5f, rr, -1.25f), 0.0f), 1.0f);
        const float tt3 = tt * tt * tt;
        const float yv  = fmaf(fmaf(fmaf(-6.0f, tt, 15.0f), tt, -10.0f), tt3, 1.0f);

        float4 v;
        v.x = fmaf(yv, o[4], o[0]);
        v.y = fmaf(yv, o[5], o[1]);
        v.z = fmaf(yv, o[6], o[2]);
        v.w = fmaf(yv, o[7], o[3]);
        g_ctab[gid] = v;
        return;
    }

    // ---- s(theta) table blocks: 1 eval/thread, LDS-staged phi weights ----
    __shared__ float pW1[30], pb1[15], pW2[225], pb2[15],
                     pW3[225], pb3[15], pW4[60], pb4[4];
    __shared__ float sv[256];
    for (int i = t; i < 225; i += 256) { pW2[i] = Wp2[i]; pW3[i] = Wp3[i]; }
    if (t < 60) pW4[t] = Wp4[t];
    if (t < 30) pW1[t] = Wp1[t];
    if (t < 15) { pb1[t] = bp1[t]; pb2[t] = bp2[t]; pb3[t] = bp3[t]; }
    if (t < 4)  pb4[t] = bp4[t];
    __syncthreads();

    const int blk = blockIdx.x - WBLK;
    const int ev  = blk * 255 + t;              // eval index for p_{ev}
    const int evc = ev < TABN ? ev : TABN;      // clamp; extra evals harmless
    const float hh = 4.0f / (float)TABN;
    const float pe = -2.0f + hh * (float)evc;
    sv[t] = s_of_p(pe, pW1, pb1, pW2, pb2, pW3, pb3, pW4, pb4);
    __syncthreads();
    if (t < 255) {
        const int cell = blk * 255 + t;
        if (cell < TABN) {
            float2 e; e.x = sv[t]; e.y = sv[t + 1] - sv[t];
            g_stab2[cell] = e;
        }
    }
}

// Cell-quad packing: node table -> 32 B/cell {c00 f32x4, d10 bf16x4, d01
// bf16x4}. Coalesced reads/writes, ~1.5us. Separate launch = visibility of
// g_ctab across XCDs. NN=256: node index is shifts only.
__global__ __launch_bounds__(256) void pack_kernel() {
    const int c = blockIdx.x * 256 + threadIdx.x;
    if (c >= NCELLS) return;
    const int ix = c % NC, iy = c / NC;
    const int n = (iy << 8) + ix;
    const float4 c00 = g_ctab[n];
    const float4 c10 = g_ctab[n + 1];
    const float4 c01 = g_ctab[n + NN];
    float4 d;
    d.x = __uint_as_float(bf16x2(c10.x - c00.x, c10.y - c00.y));
    d.y = __uint_as_float(bf16x2(c10.z - c00.z, c10.w - c00.w));
    d.z = __uint_as_float(bf16x2(c01.x - c00.x, c01.y - c00.y));
    d.w = __uint_as_float(bf16x2(c01.z - c00.z, c01.w - c00.w));
    g_qtab[2 * c]     = c00;
    g_qtab[2 * c + 1] = d;
}

// 2 points per thread. Per point: ONE aligned 32 B quad load, one 8 B
// s(theta) gather (16 KB table, L1-resident), ~60 VALU.
__global__ __launch_bounds__(256) void interior_kernel(
    const float4* __restrict__ x,      // two points per float4
    const float*  __restrict__ imv,
    const float*  __restrict__ lmbd,
    float* __restrict__ out, int n2)   // n2 = n/2
{
    const int idx = blockIdx.x * blockDim.x + threadIdx.x;
    if (idx >= n2) return;

    const float4 xx = x[idx];
    const float X0[2] = {xx.x, xx.z};
    const float X1[2] = {xx.y, xx.w};
    const float im0 = imv[0], im1 = imv[1], lam = lmbd[0];

    const float4* __restrict__ Q = g_qtab;

    float res[2];
    #pragma unroll
    for (int p = 0; p < 2; ++p) {
        const float x0 = X0[p], x1 = X1[p];

        // ---- one-line gather of the folded cell quad ----
        const float fx = x0 * (float)NC;
        const float fy = x1 * (float)NC;
        int ix = (int)fx; ix = ix < 0 ? 0 : (ix > NC - 1 ? NC - 1 : ix);
        int iy = (int)fy; iy = iy < 0 ? 0 : (iy > NC - 1 ? NC - 1 : iy);
        const float frx = fx - (float)ix;
        const float fry = fy - (float)iy;

        const int cell = iy * NC + ix;
        const float4 c00 = Q[2 * cell];
        const float4 dd  = Q[2 * cell + 1];
        const unsigned ux = __float_as_uint(dd.x), uy = __float_as_uint(dd.y);
        const unsigned uz = __float_as_uint(dd.z), uw = __float_as_uint(dd.w);

        float cv[4];
        cv[0] = fmaf(frx, __uint_as_float(ux << 16),
                fmaf(fry, __uint_as_float(uz << 16),          c00.x));
        cv[1] = fmaf(frx, __uint_as_float(ux & 0xFFFF0000u),
                fmaf(fry, __uint_as_float(uz & 0xFFFF0000u),  c00.y));
        cv[2] = fmaf(frx, __uint_as_float(uy << 16),
                fmaf(fry, __uint_as_float(uw << 16),          c00.z));
        cv[3] = fmaf(frx, __uint_as_float(uy & 0xFFFF0000u),
                fmaf(fry, __uint_as_float(uw & 0xFFFF0000u),  c00.w));

        // ---- geometry about the interior vertex ----
        const float dx = x0 - im0, dy = x1 - im1;
        const float r  = sqrtf(fmaf(dx, dx, dy * dy));

        // yita(r) -- exact, still needed for the sp term
        const float t  = fminf(fmaxf(fmaf(2.5f, r, -1.25f), 0.0f), 1.0f);
        const float t3 = t * t * t;
        const float yv = fmaf(fmaf(fmaf(-6.0f, t, 15.0f), t, -10.0f), t3, 1.0f);

        // r^lambda (sqrt fast path for lambda == 0.5)
        float rl;
        if (lam == 0.5f) rl = sqrtf(r);
        else rl = __builtin_amdgcn_exp2f(lam * __builtin_amdgcn_logf(fmaxf(r, 1e-20f)));

        // diamond-angle parameter p(theta) in [-2,2], no trig
        const float l1n = fmaxf(fabsf(dx) + fabsf(dy), 1e-20f);
        const float u   = dy * __builtin_amdgcn_rcpf(l1n);
        const float pbk = (dy >= 0.0f) ? (2.0f - u) : (-2.0f - u);
        const float pth = (dx >= 0.0f) ? u : pbk;

        // s(theta) table gather: cell {s, ds}, one 8 B load
        const float fi = fminf(fmaxf(fmaf(pth, (float)(TABN / 4), (float)(TABN / 2)),
                                     0.0f), (float)TABN - 0.001f);
        const int   ii = (int)fi;
        const float fr = fi - (float)ii;
        const float2 sd = g_stab2[ii];
        const float sval = fmaf(fr, sd.y, sd.x);

        // singular functions at x (about origin), algebraically reduced:
        // vp0 = r0^0.5 sin(th/2) = copysign(sqrt((r0-x0)/2), x1)
        // vp1 = x1
        // vp2 = r0^1.5 sin(1.5 th) = x1*sqrt((r0+x0)/2) + x0*vp0
        const float r0 = sqrtf(fmaf(x0, x0, x1 * x1));
        const float Aq = sqrtf(fmaxf(0.0f, (r0 - x0) * 0.5f));
        const float Bq = sqrtf(fmaxf(0.0f, (r0 + x0) * 0.5f));
        const float vp0 = copysignf(Aq, x1);
        const float vp2 = fmaf(x1, Bq, x0 * vp0);

        // combine (yita already folded into cv[])
        float rp = cv[0];
        rp = fmaf(cv[1], vp0, rp);
        rp = fmaf(cv[2], x1, rp);
        rp = fmaf(cv[3], vp2, rp);
        res[p] = fmaf(sval * yv, rl, rp);
    }

    float2 o; o.x = res[0]; o.y = res[1];
    ((float2*)out)[idx] = o;
}

extern "C" void kernel_launch(void* const* d_in, const int* in_sizes, int n_in,
                              void* d_out, int out_size, void* d_ws, size_t ws_size,
                              hipStream_t stream) {
    const float4* x   = (const float4*)d_in[0];
    const float* imv  = (const float*)d_in[1];
    const float* lmbd = (const float*)d_in[2];
    const float* Ww1  = (const float*)d_in[3];
    const float* bw1  = (const float*)d_in[4];
    const float* Ww2  = (const float*)d_in[5];
    const float* bw2  = (const float*)d_in[6];
    const float* Ww3  = (const float*)d_in[7];
    const float* bw3  = (const float*)d_in[8];
    const float* Ww4  = (const float*)d_in[9];
    const float* bw4  = (const float*)d_in[10];
    const float* Wp1  = (const float*)d_in[11];
    const float* bp1  = (const float*)d_in[12];
    const float* Wp2  = (const float*)d_in[13];
    const float* bp2  = (const float*)d_in[14];
    const float* Wp3  = (const float*)d_in[15];
    const float* bp3  = (const float*)d_in[16];
    const float* Wp4  = (const float*)d_in[17];
    const float* bp4  = (const float*)d_in[18];
    float* out = (float*)d_out;

    const int n  = in_sizes[0] / 2;
    const int n2 = n / 2;

    // prep (w-grid: 256 fat blocks + s-table: 9) -> pack -> interior.
    prep_kernel<<<WBLK + SBLK, 256, 0, stream>>>(
        imv,
        Ww1, bw1, Ww2, bw2, Ww3, bw3, Ww4, bw4,
        Wp1, bp1, Wp2, bp2, Wp3, bp3, Wp4, bp4);

    pack_kernel<<<(NCELLS + 255) / 256, 256, 0, stream>>>();

    const int block = 256;
    const int grid = (n2 + block - 1) / block;
    interior_kernel<<<grid, block, 0, stream>>>(x, imv, lmbd, out, n2);
}